// Round 1
// baseline (121.502 us; speedup 1.0000x reference)
//
#include <hip/hip_runtime.h>
#include <math.h>

// ChamferLossWholeImage: N=2000 render points vs 256x256 pixel grid.
// out = sum_n min_m d(n,m) + sum_m min_n d(n,m), d = L2 distance.
//
// Direction 1 (per-point min over pixels): pixels form a regular integer
// grid, so nearest pixel = clamp(rint(p)) -> O(N) closed form.
// Direction 2 (per-pixel min over points): brute force O(N*M) but on d^2
// (sqrt only once per pixel). VALU-bound, ~131M distance evals.

#define GRID_W 256

__global__ void zero_out_kernel(float* out) {
    if (threadIdx.x == 0) out[0] = 0.0f;
}

// One block per image row, one thread per pixel column.
__global__ __launch_bounds__(256) void pixel_min_kernel(
    const float* __restrict__ pts, int N, float* __restrict__ out) {
    __shared__ float spx[2048];
    __shared__ float spy[2048];
    __shared__ float red[4];

    const float px = (float)threadIdx.x;   // x = column
    const float py = (float)blockIdx.x;    // y = row

    const float INF = 3.4e38f;
    float m0 = INF, m1 = INF, m2 = INF, m3 = INF;

    for (int base = 0; base < N; base += 2048) {
        const int cnt = min(2048, N - base);
        __syncthreads();
        for (int j = threadIdx.x; j < cnt; j += 256) {
            spx[j] = pts[2 * (base + j)];
            spy[j] = pts[2 * (base + j) + 1];
        }
        __syncthreads();

        int j = 0;
        // 4 independent accumulators: break the fmin dependency chain,
        // give the scheduler ILP to hide LDS broadcast latency.
        for (; j + 4 <= cnt; j += 4) {
            float dx0 = spx[j + 0] - px, dy0 = spy[j + 0] - py;
            float dx1 = spx[j + 1] - px, dy1 = spy[j + 1] - py;
            float dx2 = spx[j + 2] - px, dy2 = spy[j + 2] - py;
            float dx3 = spx[j + 3] - px, dy3 = spy[j + 3] - py;
            m0 = fminf(m0, fmaf(dx0, dx0, dy0 * dy0));
            m1 = fminf(m1, fmaf(dx1, dx1, dy1 * dy1));
            m2 = fminf(m2, fmaf(dx2, dx2, dy2 * dy2));
            m3 = fminf(m3, fmaf(dx3, dx3, dy3 * dy3));
        }
        for (; j < cnt; ++j) {
            float dx = spx[j] - px, dy = spy[j] - py;
            m0 = fminf(m0, fmaf(dx, dx, dy * dy));
        }
    }

    float mind2 = fminf(fminf(m0, m1), fminf(m2, m3));
    float d = sqrtf(mind2);

    // wave-64 shuffle reduction
    for (int off = 32; off > 0; off >>= 1)
        d += __shfl_down(d, off, 64);

    const int lane = threadIdx.x & 63;
    const int wid  = threadIdx.x >> 6;
    if (lane == 0) red[wid] = d;
    __syncthreads();
    if (threadIdx.x == 0)
        atomicAdd(out, red[0] + red[1] + red[2] + red[3]);
}

// Per-point nearest pixel is closed-form on a regular grid.
__global__ __launch_bounds__(256) void point_min_kernel(
    const float* __restrict__ pts, int N, int H, int W, float* __restrict__ out) {
    __shared__ float red[4];
    float s = 0.0f;
    for (int i = threadIdx.x; i < N; i += 256) {
        float px = pts[2 * i], py = pts[2 * i + 1];
        float nx = fminf(fmaxf(rintf(px), 0.0f), (float)(W - 1));
        float ny = fminf(fmaxf(rintf(py), 0.0f), (float)(H - 1));
        float dx = px - nx, dy = py - ny;
        s += sqrtf(fmaf(dx, dx, dy * dy));
    }
    for (int off = 32; off > 0; off >>= 1)
        s += __shfl_down(s, off, 64);
    const int lane = threadIdx.x & 63;
    const int wid  = threadIdx.x >> 6;
    if (lane == 0) red[wid] = s;
    __syncthreads();
    if (threadIdx.x == 0)
        atomicAdd(out, red[0] + red[1] + red[2] + red[3]);
}

extern "C" void kernel_launch(void* const* d_in, const int* in_sizes, int n_in,
                              void* d_out, int out_size, void* d_ws, size_t ws_size,
                              hipStream_t stream) {
    const float* pts = (const float*)d_in[0];
    const int N = in_sizes[0] / 2;          // (N,2) points
    const int W = GRID_W;
    const int H = in_sizes[1] / W;          // img_ref is (H,W)
    float* out = (float*)d_out;

    zero_out_kernel<<<1, 64, 0, stream>>>(out);
    pixel_min_kernel<<<H, 256, 0, stream>>>(pts, N, out);
    point_min_kernel<<<1, 256, 0, stream>>>(pts, N, H, W, out);
}

// Round 2
// 71.231 us; speedup vs baseline: 1.7057x; 1.7057x over previous
//
#include <hip/hip_runtime.h>
#include <math.h>

// ChamferLossWholeImage: N=2000 render points vs 256x256 pixel grid.
// out = sum_n min_m d(n,m) + sum_m min_n d(n,m), d = L2 distance.
//
// Point side: nearest pixel on a regular integer grid is closed-form.
// Pixel side: brute force on d^2, split over C point-chunks for occupancy,
// combined with atomicMin on float-bit-pattern (valid: d^2 >= 0).
// Each thread owns 4 rows x 2 cols = 8 pixels -> 3.0 VALU ops per
// pixel-point pair and one ds_read_b64 per point per 8 pairs.

#define NCHUNK 16
#define SP_CAP 512
#define GRID_W 256

__global__ __launch_bounds__(256) void chamfer_pixel_chunk(
    const float* __restrict__ pts, int N, int chunkLen,
    unsigned int* __restrict__ wsmin, float* __restrict__ out) {
    // zero the scalar output once; reduce kernel (later in stream) atomicAdds
    if (blockIdx.x == 0 && blockIdx.y == 0 && threadIdx.x == 0) out[0] = 0.0f;

    __shared__ float2 sp[SP_CAP];
    const int base = blockIdx.y * chunkLen;
    const int cnt  = min(chunkLen, N - base);
    if (cnt <= 0) return;  // uniform per block

    for (int j = threadIdx.x; j < cnt; j += 256)
        sp[j] = ((const float2*)pts)[base + j];
    __syncthreads();

    const int t = threadIdx.x;
    const float c0 = (float)(2 * (t & 127));
    const float c1 = c0 + 1.0f;
    const int rbase = blockIdx.x * 8 + (t >> 7) * 4;
    const float r0 = (float)rbase;
    const float r1 = (float)(rbase + 1);
    const float r2 = (float)(rbase + 2);
    const float r3 = (float)(rbase + 3);

    const float INF = 3.4e38f;
    float m00 = INF, m01 = INF, m10 = INF, m11 = INF;
    float m20 = INF, m21 = INF, m30 = INF, m31 = INF;

#pragma unroll 2
    for (int j = 0; j < cnt; ++j) {
        const float2 p = sp[j];
        const float dx0 = p.x - c0, dx1 = p.x - c1;
        const float dxs0 = dx0 * dx0, dxs1 = dx1 * dx1;
        float dy;
        dy = p.y - r0;
        m00 = fminf(m00, fmaf(dy, dy, dxs0));
        m01 = fminf(m01, fmaf(dy, dy, dxs1));
        dy = p.y - r1;
        m10 = fminf(m10, fmaf(dy, dy, dxs0));
        m11 = fminf(m11, fmaf(dy, dy, dxs1));
        dy = p.y - r2;
        m20 = fminf(m20, fmaf(dy, dy, dxs0));
        m21 = fminf(m21, fmaf(dy, dy, dxs1));
        dy = p.y - r3;
        m30 = fminf(m30, fmaf(dy, dy, dxs0));
        m31 = fminf(m31, fmaf(dy, dy, dxs1));
    }

    const int ci0 = 2 * (t & 127);
    unsigned int* w0 = wsmin + rbase * GRID_W + ci0;
    atomicMin(w0 + 0 * GRID_W + 0, __float_as_uint(m00));
    atomicMin(w0 + 0 * GRID_W + 1, __float_as_uint(m01));
    atomicMin(w0 + 1 * GRID_W + 0, __float_as_uint(m10));
    atomicMin(w0 + 1 * GRID_W + 1, __float_as_uint(m11));
    atomicMin(w0 + 2 * GRID_W + 0, __float_as_uint(m20));
    atomicMin(w0 + 2 * GRID_W + 1, __float_as_uint(m21));
    atomicMin(w0 + 3 * GRID_W + 0, __float_as_uint(m30));
    atomicMin(w0 + 3 * GRID_W + 1, __float_as_uint(m31));
}

__global__ __launch_bounds__(256) void chamfer_reduce(
    const unsigned int* __restrict__ wsmin, const float* __restrict__ pts,
    int N, int H, int W, float* __restrict__ out) {
    __shared__ float red[4];
    const int gid = blockIdx.x * 256 + threadIdx.x;
    float s = 0.0f;

    if (gid * 4 < H * W) {
        uint4 v = ((const uint4*)wsmin)[gid];
        s = sqrtf(__uint_as_float(v.x)) + sqrtf(__uint_as_float(v.y)) +
            sqrtf(__uint_as_float(v.z)) + sqrtf(__uint_as_float(v.w));
    }

    if (blockIdx.x == 0) {  // point-side closed form: nearest pixel = clamp(rint(p))
        for (int i = threadIdx.x; i < N; i += 256) {
            float2 p = ((const float2*)pts)[i];
            float nx = fminf(fmaxf(rintf(p.x), 0.0f), (float)(W - 1));
            float ny = fminf(fmaxf(rintf(p.y), 0.0f), (float)(H - 1));
            float dx = p.x - nx, dy = p.y - ny;
            s += sqrtf(fmaf(dx, dx, dy * dy));
        }
    }

    for (int off = 32; off > 0; off >>= 1)
        s += __shfl_down(s, off, 64);
    const int lane = threadIdx.x & 63;
    const int wid  = threadIdx.x >> 6;
    if (lane == 0) red[wid] = s;
    __syncthreads();
    if (threadIdx.x == 0)
        atomicAdd(out, red[0] + red[1] + red[2] + red[3]);
}

extern "C" void kernel_launch(void* const* d_in, const int* in_sizes, int n_in,
                              void* d_out, int out_size, void* d_ws, size_t ws_size,
                              hipStream_t stream) {
    const float* pts = (const float*)d_in[0];
    const int N = in_sizes[0] / 2;       // (N,2) points
    const int W = GRID_W;
    const int H = in_sizes[1] / W;       // img_ref is (H,W)
    float* out = (float*)d_out;
    unsigned int* wsmin = (unsigned int*)d_ws;

    // init per-pixel min buffer to 0xFFFFFFFF (> any nonneg float bits)
    hipMemsetAsync(d_ws, 0xFF, (size_t)H * W * sizeof(unsigned int), stream);

    const int chunkLen = (N + NCHUNK - 1) / NCHUNK;
    dim3 grid(H / 8, NCHUNK);
    chamfer_pixel_chunk<<<grid, 256, 0, stream>>>(pts, N, chunkLen, wsmin, out);

    const int rblocks = (H * W / 4 + 255) / 256;
    chamfer_reduce<<<rblocks, 256, 0, stream>>>(wsmin, pts, N, H, W, out);
}

// Round 3
// 70.386 us; speedup vs baseline: 1.7262x; 1.0120x over previous
//
#include <hip/hip_runtime.h>
#include <math.h>

// ChamferLossWholeImage: N=2000 render points vs 256x256 pixel grid.
// out = sum_n min_m d(n,m) + sum_m min_n d(n,m), d = L2 distance.
//
// Point side: nearest pixel on a regular integer grid is closed-form.
// Pixel side: brute force on d^2, split over NCHUNK point-chunks for
// occupancy. Each (pixel-tile, chunk) block writes partial mins to its OWN
// ws slot (plain coalesced stores -> no atomics, no ws init). A reduce
// kernel folds the NCHUNK partials, takes sqrt, and sums.
// NOTE: the harness re-poisons the 256 MiB d_ws at ~40 us every timed
// iteration (fillBufferAligned @84% HBM peak in rocprof) -- that is a fixed
// floor outside this file's control.

#define GRID_W 256
#define NCHUNK 32
#define SP_CAP 256

__global__ __launch_bounds__(256) void chamfer_pixel_partial(
    const float* __restrict__ pts, int N, int chunkLen, int M,
    float* __restrict__ wspart, float* __restrict__ out) {
    // zero the scalar output once; reduce kernel (next in stream) atomicAdds
    if (blockIdx.x == 0 && blockIdx.y == 0 && threadIdx.x == 0) out[0] = 0.0f;

    __shared__ float2 sp[SP_CAP];
    const int base = blockIdx.y * chunkLen;
    const int cnt  = min(chunkLen, N - base);   // may be <= 0: mins stay INF

    for (int j = threadIdx.x; j < cnt; j += 256)
        sp[j] = ((const float2*)pts)[base + j];
    __syncthreads();

    const int t = threadIdx.x;
    const int ci0 = 2 * (t & 127);
    const float c0 = (float)ci0;
    const float c1 = c0 + 1.0f;
    const int rbase = blockIdx.x * 8 + (t >> 7) * 4;
    const float r0 = (float)rbase;
    const float r1 = (float)(rbase + 1);
    const float r2 = (float)(rbase + 2);
    const float r3 = (float)(rbase + 3);

    const float INF = 3.4e38f;
    float m00 = INF, m01 = INF, m10 = INF, m11 = INF;
    float m20 = INF, m21 = INF, m30 = INF, m31 = INF;

#pragma unroll 2
    for (int j = 0; j < cnt; ++j) {
        const float2 p = sp[j];
        const float dx0 = p.x - c0, dx1 = p.x - c1;
        const float dxs0 = dx0 * dx0, dxs1 = dx1 * dx1;
        float dy;
        dy = p.y - r0;
        m00 = fminf(m00, fmaf(dy, dy, dxs0));
        m01 = fminf(m01, fmaf(dy, dy, dxs1));
        dy = p.y - r1;
        m10 = fminf(m10, fmaf(dy, dy, dxs0));
        m11 = fminf(m11, fmaf(dy, dy, dxs1));
        dy = p.y - r2;
        m20 = fminf(m20, fmaf(dy, dy, dxs0));
        m21 = fminf(m21, fmaf(dy, dy, dxs1));
        dy = p.y - r3;
        m30 = fminf(m30, fmaf(dy, dy, dxs0));
        m31 = fminf(m31, fmaf(dy, dy, dxs1));
    }

    // coalesced float2 stores into this chunk's private slab
    float2* w = (float2*)(wspart + (size_t)blockIdx.y * M) +
                (size_t)rbase * (GRID_W / 2) + (ci0 >> 1);
    const int rs = GRID_W / 2;
    w[0 * rs] = make_float2(m00, m01);
    w[1 * rs] = make_float2(m10, m11);
    w[2 * rs] = make_float2(m20, m21);
    w[3 * rs] = make_float2(m30, m31);
}

__global__ __launch_bounds__(256) void chamfer_reduce(
    const float* __restrict__ wspart, const float* __restrict__ pts,
    int N, int M, int H, int W, float* __restrict__ out) {
    __shared__ float red[4];
    const int gid = blockIdx.x * 256 + threadIdx.x;

    const float INF = 3.4e38f;
    float m0 = INF, m1 = INF, m2 = INF, m3 = INF;
#pragma unroll
    for (int c = 0; c + 4 <= NCHUNK; c += 4) {
        m0 = fminf(m0, wspart[(size_t)(c + 0) * M + gid]);
        m1 = fminf(m1, wspart[(size_t)(c + 1) * M + gid]);
        m2 = fminf(m2, wspart[(size_t)(c + 2) * M + gid]);
        m3 = fminf(m3, wspart[(size_t)(c + 3) * M + gid]);
    }
    float s = sqrtf(fminf(fminf(m0, m1), fminf(m2, m3)));

    if (blockIdx.x == 0) {  // point side: nearest pixel = clamp(rint(p))
        for (int i = threadIdx.x; i < N; i += 256) {
            float2 p = ((const float2*)pts)[i];
            float nx = fminf(fmaxf(rintf(p.x), 0.0f), (float)(W - 1));
            float ny = fminf(fmaxf(rintf(p.y), 0.0f), (float)(H - 1));
            float dx = p.x - nx, dy = p.y - ny;
            s += sqrtf(fmaf(dx, dx, dy * dy));
        }
    }

    for (int off = 32; off > 0; off >>= 1)
        s += __shfl_down(s, off, 64);
    const int lane = threadIdx.x & 63;
    const int wid  = threadIdx.x >> 6;
    if (lane == 0) red[wid] = s;
    __syncthreads();
    if (threadIdx.x == 0)
        atomicAdd(out, red[0] + red[1] + red[2] + red[3]);
}

extern "C" void kernel_launch(void* const* d_in, const int* in_sizes, int n_in,
                              void* d_out, int out_size, void* d_ws, size_t ws_size,
                              hipStream_t stream) {
    const float* pts = (const float*)d_in[0];
    const int N = in_sizes[0] / 2;       // (N,2) points
    const int W = GRID_W;
    const int H = in_sizes[1] / W;       // img_ref is (H,W)
    const int M = H * W;
    float* out = (float*)d_out;
    float* wspart = (float*)d_ws;        // NCHUNK * M floats = 8 MB

    const int chunkLen = (N + NCHUNK - 1) / NCHUNK;
    dim3 grid(H / 8, NCHUNK);
    chamfer_pixel_partial<<<grid, 256, 0, stream>>>(pts, N, chunkLen, M, wspart, out);

    chamfer_reduce<<<M / 256, 256, 0, stream>>>(wspart, pts, N, M, H, W, out);
}